// Round 1
// baseline (2023.309 us; speedup 1.0000x reference)
//
#include <hip/hip_runtime.h>
#include <math.h>

typedef __attribute__((ext_vector_type(8))) short bf16x8;
typedef __attribute__((ext_vector_type(4))) float f32x4;
typedef __attribute__((ext_vector_type(4))) unsigned int u32x4;
typedef __attribute__((ext_vector_type(4))) unsigned short u16x4;

static constexpr int Tn = 2048;
static constexpr int Dm = 256;
static constexpr int NHn = 4;
static constexpr int Ln = 4;
static constexpr int DFFn = 1024;
static constexpr int Vn = 32000;
static constexpr int BTn = 4096;   // B*T

__device__ __forceinline__ unsigned short f2bf(float f) {
  unsigned int u = __float_as_uint(f);
  u += 0x7fffu + ((u >> 16) & 1u);
  return (unsigned short)(u >> 16);
}

// ---------------- fp32 -> bf16 convert (x4 vectorized) ----------------
__global__ __launch_bounds__(256) void cvt_f2bf(const float* __restrict__ in,
                                                unsigned short* __restrict__ out, int n) {
  int i = (blockIdx.x * 256 + threadIdx.x) * 4;
  if (i >= n) return;
  float4 v = *reinterpret_cast<const float4*>(in + i);
  u16x4 o;
  o[0] = f2bf(v.x); o[1] = f2bf(v.y); o[2] = f2bf(v.z); o[3] = f2bf(v.w);
  *reinterpret_cast<u16x4*>(out + i) = o;
}

// ---------------- embedding + positional encoding ----------------
__global__ __launch_bounds__(256) void embed_pos(const int* __restrict__ tokens,
                                                 const float* __restrict__ emb,
                                                 float* __restrict__ xf,
                                                 unsigned short* __restrict__ xb) {
  int idx = blockIdx.x * 256 + threadIdx.x;   // BTn*Dm total
  int bt = idx >> 8, d = idx & 255;
  int t = bt & (Tn - 1);
  int tok = tokens[bt];
  float v = emb[(size_t)tok * Dm + d];
  int i2 = d & ~1;
  float dv = expf((float)i2 * (-0.03597789207803249f));  // -ln(10000)/256
  float arg = (float)t * dv;
  float pe = (d & 1) ? cosf(arg) : sinf(arg);
  float x = v + pe;
  xf[idx] = x;
  xb[idx] = f2bf(x);
}

// ---------------- (optional add) + layernorm; writes fp32 + bf16 shadow ----------------
__global__ __launch_bounds__(256) void add_ln(const float* __restrict__ addend,
                                              const float* __restrict__ gam,
                                              const float* __restrict__ bet,
                                              float* __restrict__ xf,
                                              unsigned short* __restrict__ xb) {
  int row = blockIdx.x, d = threadIdx.x;   // 256 threads = D
  __shared__ float red[8];
  size_t off = (size_t)row * Dm + d;
  float u = xf[off];
  if (addend) u += addend[off];
  float tsum = u;
  #pragma unroll
  for (int o = 32; o > 0; o >>= 1) tsum += __shfl_xor(tsum, o);
  int w = d >> 6, lane = d & 63;
  if (lane == 0) red[w] = tsum;
  __syncthreads();
  float mean = (red[0] + red[1] + red[2] + red[3]) * (1.f / 256.f);
  float df = u - mean;
  float vsum = df * df;
  #pragma unroll
  for (int o = 32; o > 0; o >>= 1) vsum += __shfl_xor(vsum, o);
  if (lane == 0) red[4 + w] = vsum;
  __syncthreads();
  float var = (red[4] + red[5] + red[6] + red[7]) * (1.f / 256.f);
  float y = df * rsqrtf(var + 1e-5f) * gam[d] + bet[d];
  xf[off] = y;
  xb[off] = f2bf(y);
}

// ---------------- fp32 flash attention (causal), writes bf16 o ----------------
// qkv layout per row (bt): [q(0:256) | k(256:512) | v(512:768)], within each: h*64+dk
__global__ __launch_bounds__(256) void attn(const float* __restrict__ qkv,
                                            unsigned short* __restrict__ ob) {
  int bh = blockIdx.y;
  int b = bh >> 2, h = bh & 3;       // H=4
  int q0b = blockIdx.x * 32;         // 32 queries per block, 8 per wave
  __shared__ __align__(16) float Qs[32 * 64];
  __shared__ __align__(16) float Ks[64 * 68];
  __shared__ __align__(16) float Vs[64 * 68];
  __shared__ __align__(16) float Ps[4][8 * 68];
  int tid = threadIdx.x;
  int lane = tid & 63, w = tid >> 6;
  size_t baseQ = ((size_t)(b * Tn + q0b)) * 768 + h * 64;
  for (int idx = tid; idx < 32 * 64; idx += 256) {
    int q = idx >> 6, d = idx & 63;
    Qs[q * 64 + d] = qkv[baseQ + (size_t)q * 768 + d];
  }
  float m_i[8], l_i[8], oa[8];
  #pragma unroll
  for (int i = 0; i < 8; i++) { m_i[i] = -INFINITY; l_i[i] = 0.f; oa[i] = 0.f; }
  int jt_max = blockIdx.x >> 1;      // last kv tile with any unmasked j
  for (int jt = 0; jt <= jt_max; jt++) {
    int j0 = jt * 64;
    __syncthreads();
    size_t baseK = ((size_t)(b * Tn + j0)) * 768 + 256 + h * 64;
    for (int idx = tid; idx < 64 * 64; idx += 256) {
      int j = idx >> 6, d = idx & 63;
      Ks[j * 68 + d] = qkv[baseK + (size_t)j * 768 + d];
      Vs[j * 68 + d] = qkv[baseK + 256 + (size_t)j * 768 + d];
    }
    __syncthreads();
    // scores: lane = kv index within tile
    float s[8];
    #pragma unroll
    for (int i = 0; i < 8; i++) s[i] = 0.f;
    for (int d = 0; d < 64; d += 4) {
      float4 kv4 = *reinterpret_cast<const float4*>(&Ks[lane * 68 + d]);
      #pragma unroll
      for (int qi = 0; qi < 8; qi++) {
        float4 qv = *reinterpret_cast<const float4*>(&Qs[(w * 8 + qi) * 64 + d]);
        s[qi] = fmaf(qv.x, kv4.x, fmaf(qv.y, kv4.y, fmaf(qv.z, kv4.z, fmaf(qv.w, kv4.w, s[qi]))));
      }
    }
    int jg = j0 + lane;
    float alpha[8];
    #pragma unroll
    for (int qi = 0; qi < 8; qi++) {
      int qg = q0b + w * 8 + qi;
      float sv = (jg <= qg) ? s[qi] * 0.125f : -INFINITY;
      float mx = sv;
      #pragma unroll
      for (int o = 32; o > 0; o >>= 1) mx = fmaxf(mx, __shfl_xor(mx, o));
      float mnew = fmaxf(m_i[qi], mx);
      float pv = __expf(sv - mnew);          // exp(-inf - finite) = 0
      float ps = pv;
      #pragma unroll
      for (int o = 32; o > 0; o >>= 1) ps += __shfl_xor(ps, o);
      alpha[qi] = __expf(m_i[qi] - mnew);    // first tile: exp(-inf) = 0
      l_i[qi] = l_i[qi] * alpha[qi] + ps;
      m_i[qi] = mnew;
      Ps[w][qi * 68 + lane] = pv;            // per-wave buffer, no barrier needed
    }
    // AV: lane = head dim d
    float accq[8];
    #pragma unroll
    for (int qi = 0; qi < 8; qi++) accq[qi] = 0.f;
    for (int j = 0; j < 64; j += 4) {
      float v0 = Vs[j * 68 + lane];
      float v1 = Vs[(j + 1) * 68 + lane];
      float v2 = Vs[(j + 2) * 68 + lane];
      float v3 = Vs[(j + 3) * 68 + lane];
      #pragma unroll
      for (int qi = 0; qi < 8; qi++) {
        float4 p4 = *reinterpret_cast<const float4*>(&Ps[w][qi * 68 + j]);
        accq[qi] = fmaf(p4.x, v0, fmaf(p4.y, v1, fmaf(p4.z, v2, fmaf(p4.w, v3, accq[qi]))));
      }
    }
    #pragma unroll
    for (int qi = 0; qi < 8; qi++) oa[qi] = oa[qi] * alpha[qi] + accq[qi];
  }
  #pragma unroll
  for (int qi = 0; qi < 8; qi++) {
    int qg = q0b + w * 8 + qi;
    float o = oa[qi] / l_i[qi];
    ob[((size_t)(b * Tn + qg)) * Dm + h * 64 + lane] = f2bf(o);
  }
}

// ---------------- bf16 MFMA GEMM: C[M,N] = A[M,K] * W[N,K]^T + bias ----------------
// EPI 0: fp32 out.  EPI 1: bf16(relu(out)).
template <int EPI>
__global__ __launch_bounds__(256) void gemm_bt(const unsigned short* __restrict__ A,
                                               const unsigned short* __restrict__ W,
                                               const float* __restrict__ bias,
                                               float* __restrict__ Cf,
                                               unsigned short* __restrict__ Cb,
                                               int M, int N, int K) {
  constexpr int LDA = 40;  // 32 + 8 pad (bf16 elems): breaks pow-2 bank stride
  __shared__ __align__(16) unsigned short As[128 * LDA];
  __shared__ __align__(16) unsigned short Bs[128 * LDA];
  int tid = threadIdx.x;
  int lane = tid & 63, w = tid >> 6;
  int wm = (w >> 1) * 64, wn = (w & 1) * 64;
  int r = lane & 15, quad = lane >> 4;
  int m0 = blockIdx.y * 128, n0 = blockIdx.x * 128;
  f32x4 acc[4][4];
  #pragma unroll
  for (int i = 0; i < 4; i++)
    #pragma unroll
    for (int j = 0; j < 4; j++) acc[i][j] = (f32x4){0.f, 0.f, 0.f, 0.f};
  int row0 = tid >> 2, s4 = (tid & 3) * 8;
  for (int k0 = 0; k0 < K; k0 += 32) {
    __syncthreads();
    #pragma unroll
    for (int i = 0; i < 2; i++) {
      int row = row0 + i * 64;
      u32x4 va = *reinterpret_cast<const u32x4*>(A + (size_t)(m0 + row) * K + k0 + s4);
      *reinterpret_cast<u32x4*>(&As[row * LDA + s4]) = va;
      u32x4 vb = *reinterpret_cast<const u32x4*>(W + (size_t)(n0 + row) * K + k0 + s4);
      *reinterpret_cast<u32x4*>(&Bs[row * LDA + s4]) = vb;
    }
    __syncthreads();
    bf16x8 af[4], bfr[4];
    #pragma unroll
    for (int mi = 0; mi < 4; mi++)
      af[mi] = *reinterpret_cast<const bf16x8*>(&As[(wm + mi * 16 + r) * LDA + quad * 8]);
    #pragma unroll
    for (int ni = 0; ni < 4; ni++)
      bfr[ni] = *reinterpret_cast<const bf16x8*>(&Bs[(wn + ni * 16 + r) * LDA + quad * 8]);
    #pragma unroll
    for (int mi = 0; mi < 4; mi++)
      #pragma unroll
      for (int ni = 0; ni < 4; ni++)
        acc[mi][ni] = __builtin_amdgcn_mfma_f32_16x16x32_bf16(af[mi], bfr[ni], acc[mi][ni], 0, 0, 0);
  }
  #pragma unroll
  for (int mi = 0; mi < 4; mi++) {
    #pragma unroll
    for (int ni = 0; ni < 4; ni++) {
      int n = n0 + wn + ni * 16 + r;          // C/D: col = lane&15
      float bv = bias[n];
      #pragma unroll
      for (int rr = 0; rr < 4; rr++) {
        int m = m0 + wm + mi * 16 + quad * 4 + rr;   // C/D: row = quad*4+reg
        float v = acc[mi][ni][rr] + bv;
        if (EPI == 0) {
          Cf[(size_t)m * N + n] = v;
        } else {
          Cb[(size_t)m * N + n] = f2bf(fmaxf(v, 0.f));
        }
      }
    }
  }
}

extern "C" void kernel_launch(void* const* d_in, const int* in_sizes, int n_in,
                              void* d_out, int out_size, void* d_ws, size_t ws_size,
                              hipStream_t stream) {
  (void)in_sizes; (void)n_in; (void)out_size; (void)ws_size;
  const int* tokens = (const int*)d_in[0];
  const float* emb = (const float*)d_in[1];
  const float* qkv_w = (const float*)d_in[2];
  const float* qkv_b = (const float*)d_in[3];
  const float* fc_w = (const float*)d_in[4];
  const float* fc_b = (const float*)d_in[5];
  const float* ln1_s = (const float*)d_in[6];
  const float* ln1_b = (const float*)d_in[7];
  const float* w1 = (const float*)d_in[8];
  const float* b1 = (const float*)d_in[9];
  const float* w2 = (const float*)d_in[10];
  const float* b2 = (const float*)d_in[11];
  const float* ln2_s = (const float*)d_in[12];
  const float* ln2_b = (const float*)d_in[13];
  const float* lnf_s = (const float*)d_in[14];
  const float* lnf_b = (const float*)d_in[15];
  const float* out_w = (const float*)d_in[16];
  const float* out_b = (const float*)d_in[17];
  float* logits = (float*)d_out;

  char* p = (char*)d_ws;
  auto carve = [&](size_t bytes) {
    char* r = p;
    p += (bytes + 255) & ~(size_t)255;
    return r;
  };
  float* xf = (float*)carve((size_t)BTn * Dm * 4);
  unsigned short* xb = (unsigned short*)carve((size_t)BTn * Dm * 2);
  float* qkvf = (float*)carve((size_t)BTn * 768 * 4);
  unsigned short* obb = (unsigned short*)carve((size_t)BTn * Dm * 2);
  float* of = (float*)carve((size_t)BTn * Dm * 4);
  unsigned short* hb = (unsigned short*)carve((size_t)BTn * DFFn * 2);
  float* ff = (float*)carve((size_t)BTn * Dm * 4);
  unsigned short* wqkvb = (unsigned short*)carve((size_t)Ln * 768 * Dm * 2);
  unsigned short* wfcb = (unsigned short*)carve((size_t)Ln * Dm * Dm * 2);
  unsigned short* w1b = (unsigned short*)carve((size_t)Ln * DFFn * Dm * 2);
  unsigned short* w2b = (unsigned short*)carve((size_t)Ln * Dm * DFFn * 2);
  unsigned short* outwb = (unsigned short*)carve((size_t)Vn * Dm * 2);

  auto cvt = [&](const float* src, unsigned short* dst, int n) {
    cvt_f2bf<<<dim3((n / 4 + 255) / 256), dim3(256), 0, stream>>>(src, dst, n);
  };
  cvt(qkv_w, wqkvb, Ln * 768 * Dm);
  cvt(fc_w, wfcb, Ln * Dm * Dm);
  cvt(w1, w1b, Ln * DFFn * Dm);
  cvt(w2, w2b, Ln * Dm * DFFn);
  cvt(out_w, outwb, Vn * Dm);

  embed_pos<<<dim3(BTn), dim3(256), 0, stream>>>(tokens, emb, xf, xb);

  for (int l = 0; l < Ln; l++) {
    gemm_bt<0><<<dim3(768 / 128, BTn / 128), dim3(256), 0, stream>>>(
        xb, wqkvb + (size_t)l * 768 * Dm, qkv_b + l * 768, qkvf, nullptr, BTn, 768, Dm);
    attn<<<dim3(Tn / 32, 2 * NHn), dim3(256), 0, stream>>>(qkvf, obb);
    gemm_bt<0><<<dim3(Dm / 128, BTn / 128), dim3(256), 0, stream>>>(
        obb, wfcb + (size_t)l * Dm * Dm, fc_b + l * Dm, of, nullptr, BTn, Dm, Dm);
    add_ln<<<dim3(BTn), dim3(256), 0, stream>>>(of, ln1_s + l * Dm, ln1_b + l * Dm, xf, xb);
    gemm_bt<1><<<dim3(DFFn / 128, BTn / 128), dim3(256), 0, stream>>>(
        xb, w1b + (size_t)l * DFFn * Dm, b1 + l * DFFn, nullptr, hb, BTn, DFFn, Dm);
    gemm_bt<0><<<dim3(Dm / 128, BTn / 128), dim3(256), 0, stream>>>(
        hb, w2b + (size_t)l * Dm * DFFn, b2 + l * Dm, ff, nullptr, BTn, Dm, DFFn);
    add_ln<<<dim3(BTn), dim3(256), 0, stream>>>(ff, ln2_s + l * Dm, ln2_b + l * Dm, xf, xb);
  }
  add_ln<<<dim3(BTn), dim3(256), 0, stream>>>(nullptr, lnf_s, lnf_b, xf, xb);

  gemm_bt<0><<<dim3(Vn / 128, BTn / 128), dim3(256), 0, stream>>>(
      xb, outwb, out_b, logits, nullptr, BTn, Vn, Dm);
}